// Round 15
// baseline (323.032 us; speedup 1.0000x reference)
//
#include <hip/hip_runtime.h>
#include <stdint.h>

#define S_LEN 2048
#define DMODEL 1024
#define NHEAD 16
#define DHEAD 64
#define NBATCH 2
#define NE 4194304   // NBATCH*S_LEN*DMODEL
#define WN 1048576   // DMODEL*DMODEL

typedef unsigned short u16;
typedef float f32x16 __attribute__((ext_vector_type(16)));
typedef __bf16 bf16x8 __attribute__((ext_vector_type(8)));

__device__ __forceinline__ u16 f2bf(float x) {
  union { float f; unsigned u; } v; v.f = x;
  unsigned r = v.u + 0x7fffu + ((v.u >> 16) & 1u);
  return (u16)(r >> 16);
}
__device__ __forceinline__ unsigned cvt_pk_bf16(float lo, float hi) {
  unsigned r;
  asm("v_cvt_pk_bf16_f32 %0, %1, %2" : "=v"(r) : "v"(lo), "v"(hi));
  return r;
}
__device__ __forceinline__ void gld_lds16(const void* g, void* l) {
  __builtin_amdgcn_global_load_lds(
      (const __attribute__((address_space(1))) unsigned*)g,
      (__attribute__((address_space(3))) unsigned*)l, 16, 0, 0);
}

// ---------------- convert q,k,v f32 -> bf16 ----------------
__global__ __launch_bounds__(256) void cvt_inputs(
    const float* __restrict__ q, const float* __restrict__ k, const float* __restrict__ v,
    u16* __restrict__ xq, u16* __restrict__ xk, u16* __restrict__ xv)
{
  int i = blockIdx.x * 256 + threadIdx.x;
  const int stride = gridDim.x * 256;
  for (; i < NE / 4; i += stride) {
    float4 a = ((const float4*)q)[i];
    float4 b = ((const float4*)k)[i];
    float4 c = ((const float4*)v)[i];
    ushort4 oa, ob, oc;
    oa.x = f2bf(a.x); oa.y = f2bf(a.y); oa.z = f2bf(a.z); oa.w = f2bf(a.w);
    ob.x = f2bf(b.x); ob.y = f2bf(b.y); ob.z = f2bf(b.z); ob.w = f2bf(b.w);
    oc.x = f2bf(c.x); oc.y = f2bf(c.y); oc.z = f2bf(c.z); oc.w = f2bf(c.w);
    ((ushort4*)xq)[i] = oa;
    ((ushort4*)xk)[i] = ob;
    ((ushort4*)xv)[i] = oc;
  }
}

// ---------------- convert + transpose weights: W[k][n] -> WT[n][k] bf16 ----------------
__global__ __launch_bounds__(256) void wtrans(
    const float* __restrict__ Wq, const float* __restrict__ Wk,
    const float* __restrict__ Wv, const float* __restrict__ Wo,
    u16* __restrict__ oq, u16* __restrict__ ok, u16* __restrict__ ov, u16* __restrict__ oo)
{
  __shared__ u16 t[64][65];
  const float* W; u16* O;
  if (blockIdx.z == 0)      { W = Wq; O = oq; }
  else if (blockIdx.z == 1) { W = Wk; O = ok; }
  else if (blockIdx.z == 2) { W = Wv; O = ov; }
  else                      { W = Wo; O = oo; }
  const int tid = threadIdx.x;
  const int r0 = blockIdx.y * 64, c0 = blockIdx.x * 64;
#pragma unroll
  for (int i = 0; i < 4; ++i) {
    const int row = i * 16 + (tid >> 4);
    const int col = (tid & 15) * 4;
    float4 wv = *(const float4*)(W + (size_t)(r0 + row) * DMODEL + c0 + col);
    t[row][col + 0] = f2bf(wv.x);
    t[row][col + 1] = f2bf(wv.y);
    t[row][col + 2] = f2bf(wv.z);
    t[row][col + 3] = f2bf(wv.w);
  }
  __syncthreads();
#pragma unroll
  for (int i = 0; i < 4; ++i) {
    const int row = i * 16 + (tid >> 4);
    const int col = (tid & 15) * 4;
    ushort4 o;
    o.x = t[col + 0][row]; o.y = t[col + 1][row];
    o.z = t[col + 2][row]; o.w = t[col + 3][row];
    *(ushort4*)(O + (size_t)(c0 + row) * DMODEL + r0 + col) = o;
  }
}

// ---------------- 128x128 bf16 MFMA GEMM, B^T input, global_load_lds staging ----------------
template <int OUTMODE>
__device__ __forceinline__ void gemm_core(
    const u16* __restrict__ A, const u16* __restrict__ Bt,
    const float* __restrict__ bias, void* __restrict__ outp,
    float scale, int m0, int n0)
{
  __shared__ u16 As[128 * 32];
  __shared__ u16 Bs[128 * 32];
  const int tid = threadIdx.x;
  const int lane = tid & 63, w = tid >> 6;
  const int q_l = lane & 31, hi = lane >> 5;
  const int wr = w >> 1, wc = w & 1;

  f32x16 acc[2][2];
#pragma unroll
  for (int a = 0; a < 2; ++a)
#pragma unroll
    for (int b = 0; b < 2; ++b)
#pragma unroll
      for (int r = 0; r < 16; ++r) acc[a][b][r] = 0.f;

  const u16* srcA = A + (size_t)(m0 + (tid >> 2)) * DMODEL + (tid & 3) * 8;
  const u16* srcB = Bt + (size_t)(n0 + (tid >> 2)) * DMODEL + (tid & 3) * 8;
  u16* dstA = As + w * 512;
  u16* dstB = Bs + w * 512;

  for (int kt = 0; kt < DMODEL; kt += 32) {
    gld_lds16(srcA + kt, dstA);
    gld_lds16(srcA + kt + (size_t)64 * DMODEL, dstA + 2048);
    gld_lds16(srcB + kt, dstB);
    gld_lds16(srcB + kt + (size_t)64 * DMODEL, dstB + 2048);
    __syncthreads();
#pragma unroll
    for (int kk = 0; kk < 2; ++kk) {
      bf16x8 af[2], bfv[2];
#pragma unroll
      for (int mb = 0; mb < 2; ++mb)
        af[mb] = *reinterpret_cast<const bf16x8*>(&As[(wr * 64 + mb * 32 + q_l) * 32 + kk * 16 + hi * 8]);
#pragma unroll
      for (int nb = 0; nb < 2; ++nb)
        bfv[nb] = *reinterpret_cast<const bf16x8*>(&Bs[(wc * 64 + nb * 32 + q_l) * 32 + kk * 16 + hi * 8]);
#pragma unroll
      for (int mb = 0; mb < 2; ++mb)
#pragma unroll
        for (int nb = 0; nb < 2; ++nb)
          acc[mb][nb] = __builtin_amdgcn_mfma_f32_32x32x16_bf16(af[mb], bfv[nb], acc[mb][nb], 0, 0, 0);
    }
    __syncthreads();
  }

#pragma unroll
  for (int mb = 0; mb < 2; ++mb) {
#pragma unroll
    for (int nb = 0; nb < 2; ++nb) {
      const int n = n0 + wc * 64 + nb * 32 + q_l;
      const float bn = bias[n];
#pragma unroll
      for (int r = 0; r < 16; ++r) {
        const int m = m0 + wr * 64 + mb * 32 + (r & 3) + 8 * (r >> 2) + 4 * hi;
        const float val = (acc[mb][nb][r] + bn) * scale;
        if (OUTMODE == 0) {
          const int bb = m >> 11, s = m & 2047, hh = n >> 6, d = n & 63;
          ((u16*)outp)[(((size_t)(bb * NHEAD + hh)) * S_LEN + s) * DHEAD + d] = f2bf(val);
        } else {
          ((float*)outp)[(size_t)m * DMODEL + n] = val;
        }
      }
    }
  }
}

__global__ __launch_bounds__(256) void gemm_qkv(
    const u16* __restrict__ xq, const u16* __restrict__ xk, const u16* __restrict__ xv,
    const u16* __restrict__ wqt, const u16* __restrict__ wkt, const u16* __restrict__ wvt,
    const float* __restrict__ bq, const float* __restrict__ bk, const float* __restrict__ bv,
    u16* __restrict__ qh, u16* __restrict__ kh, u16* __restrict__ vh)
{
  const u16 *A, *Bt; const float* bias; u16* O; float scale;
  if (blockIdx.z == 0)      { A = xq; Bt = wqt; bias = bq; O = qh; scale = 0.125f; }
  else if (blockIdx.z == 1) { A = xk; Bt = wkt; bias = bk; O = kh; scale = 1.f; }
  else                      { A = xv; Bt = wvt; bias = bv; O = vh; scale = 1.f; }
  gemm_core<0>(A, Bt, bias, O, scale, blockIdx.y * 128, blockIdx.x * 128);
}

// ---------------- transpose Vh[bh][s][d] -> Vt[bh][d][s], producer-XCD aligned ----------------
__global__ __launch_bounds__(256) void vtrans(const u16* __restrict__ vh, u16* __restrict__ vt)
{
  __shared__ u16 t[64][72];
  const int tid = threadIdx.x;
  const int id = blockIdx.x;
  const int h = ((id & 7) << 1) | ((id >> 3) & 1);
  const int b = (id >> 4) & 1;
  const int bh = b * 16 + h;
  const int s0 = (id >> 5) * 64;
  const u16* src = vh + (size_t)bh * S_LEN * DHEAD;
  u16* dst = vt + (size_t)bh * DHEAD * S_LEN;
#pragma unroll
  for (int i = 0; i < 2; ++i) {
    const int row = i * 32 + (tid >> 3);
    const int c8 = (tid & 7) * 8;
    *(uint4*)&t[row][c8] = *(const uint4*)(src + (size_t)(s0 + row) * DHEAD + c8);
  }
  __syncthreads();
#pragma unroll
  for (int i = 0; i < 2; ++i) {
    const int d = i * 32 + (tid >> 3);
    const int c8 = (tid & 7) * 8;
    unsigned p0 = (unsigned)t[c8 + 0][d] | ((unsigned)t[c8 + 1][d] << 16);
    unsigned p1 = (unsigned)t[c8 + 2][d] | ((unsigned)t[c8 + 3][d] << 16);
    unsigned p2 = (unsigned)t[c8 + 4][d] | ((unsigned)t[c8 + 5][d] << 16);
    unsigned p3 = (unsigned)t[c8 + 6][d] | ((unsigned)t[c8 + 7][d] << 16);
    uint4 o; o.x = p0; o.y = p1; o.z = p2; o.w = p3;
    *(uint4*)(dst + (size_t)d * S_LEN + s0 + c8) = o;
  }
}

// ---------------- attn kernel A v9: L1-shared waves + drift-clamp barriers ----------
// R14 structure (4 waves/block, same k-sweep, different q-tiles) + ONE change: a raw
// s_barrier (NO waitcnt -> prefetches stay in flight) per 3-tile group clamps inter-wave
// drift to <= 3 tiles (24KB) so waves 2-4 actually hit L1 behind wave 1. Waves share no
// memory data; the barrier is purely a timing clamp -> no memory semantics needed.
__global__ __launch_bounds__(256, 2) void attn_pv(
    const u16* __restrict__ qh, const u16* __restrict__ kh,
    const u16* __restrict__ vt, const float* __restrict__ mask,
    float* __restrict__ inv_g, u16* __restrict__ ctx_out)
{
  const int tid = threadIdx.x;
  const int lane = tid & 63, w = tid >> 6;
  const int q_l = lane & 31, hi = lane >> 5;
  const int id = blockIdx.x;               // 0..511
  const int h = ((id & 7) << 1) | ((id >> 3) & 1);
  const int b = (id >> 4) & 1;
  const int bh = b * 16 + h;
  const int qb = id >> 5;                  // 0..15
  const int q0 = qb * 128 + w * 32;        // wave-private q-tile

  const u16* Qp = qh + (size_t)bh * S_LEN * DHEAD;
  const u16* Kp = kh + (size_t)bh * S_LEN * DHEAD;
  const u16* Vp = vt + (size_t)bh * DHEAD * S_LEN;
  const float* mrow = mask + (size_t)b * S_LEN;

  bf16x8 qf[4];
  {
    const u16* qrow = Qp + (size_t)(q0 + q_l) * DHEAD + hi * 8;
#pragma unroll
    for (int c = 0; c < 4; ++c) qf[c] = *reinterpret_cast<const bf16x8*>(qrow + c * 16);
  }

  float rsum = 0.f;
  f32x16 cacc[2];
#pragma unroll
  for (int db = 0; db < 2; ++db)
#pragma unroll
    for (int r = 0; r < 16; ++r) cacc[db][r] = 0.f;

#define LDK(buf, t_) do {                                                     \
    const u16* _kr = Kp + (size_t)((t_) * 32 + q_l) * DHEAD + hi * 8;         \
    buf[0] = *reinterpret_cast<const bf16x8*>(_kr);                           \
    buf[1] = *reinterpret_cast<const bf16x8*>(_kr + 16);                      \
    buf[2] = *reinterpret_cast<const bf16x8*>(_kr + 32);                      \
    buf[3] = *reinterpret_cast<const bf16x8*>(_kr + 48);                      \
  } while (0)
#define LDV(buf, t_) do {                                                     \
    const u16* _vr = Vp + (size_t)q_l * S_LEN + (t_) * 32 + hi * 8;           \
    buf[0] = *reinterpret_cast<const bf16x8*>(_vr);                           \
    buf[1] = *reinterpret_cast<const bf16x8*>(_vr + (size_t)32 * S_LEN);      \
    buf[2] = *reinterpret_cast<const bf16x8*>(_vr + 16);                      \
    buf[3] = *reinterpret_cast<const bf16x8*>(_vr + (size_t)32 * S_LEN + 16); \
  } while (0)
#define COMPUTE(kb, vb, t_) do {                                              \
    const int _k0 = (t_) * 32;                                                \
    f32x16 _a0, _a1;                                                          \
    _Pragma("unroll") for (int _r = 0; _r < 16; ++_r) { _a0[_r] = 0.f; _a1[_r] = 0.f; } \
    _a0 = __builtin_amdgcn_mfma_f32_32x32x16_bf16(kb[0], qf[0], _a0, 0, 0, 0); \
    _a0 = __builtin_amdgcn_mfma_f32_32x32x16_bf16(kb[1], qf[1], _a0, 0, 0, 0); \
    _a1 = __builtin_amdgcn_mfma_f32_32x32x16_bf16(kb[2], qf[2], _a1, 0, 0, 0); \
    _a1 = __builtin_amdgcn_mfma_f32_32x32x16_bf16(kb[3], qf[3], _a1, 0, 0, 0); \
    float _p[16];                                                             \
    _Pragma("unroll") for (int _g = 0; _g < 4; ++_g) {                        \
      const float4 _mk = *(const float4*)&mrow[_k0 + 8 * _g + 4 * hi];        \
      _p[4*_g+0] = __expf(_a0[4*_g+0] + _a1[4*_g+0] + _mk.x * -1e9f);         \
      _p[4*_g+1] = __expf(_a0[4*_g+1] + _a1[4*_g+1] + _mk.y * -1e9f);         \
      _p[4*_g+2] = __expf(_a0[4*_g+2] + _a1[4*_g+2] + _mk.z * -1e9f);         \
      _p[4*_g+3] = __expf(_a0[4*_g+3] + _a1[4*_g+3] + _mk.w * -1e9f);         \
      rsum += (_p[4*_g+0] + _p[4*_g+1]) + (_p[4*_g+2] + _p[4*_g+3]);          \
    }                                                                         \
    unsigned _pk[8];                                                          \
    _Pragma("unroll") for (int _g = 0; _g < 4; ++_g) {                        \
      _pk[2*_g+0] = cvt_pk_bf16(_p[4*_g+0], _p[4*_g+1]);                      \
      _pk[2*_g+1] = cvt_pk_bf16(_p[4*_g+2], _p[4*_g+3]);                      \
    }                                                                         \
    _Pragma("unroll") for (int _s2 = 0; _s2 < 2; ++_s2) {                     \
      unsigned _x0 = _pk[4*_s2+0], _y0 = _pk[4*_s2+2];                        \
      unsigned _x1 = _pk[4*_s2+1], _y1 = _pk[4*_s2+3];                        \
      asm volatile("v_permlane32_swap_b32 %0, %1" : "+v"(_x0), "+v"(_y0));    \
      asm volatile("v_permlane32_swap_b32 %0, %1" : "+v"(_x1), "+v"(_y1));    \
      uint4 _fr; _fr.x = _x0; _fr.y = _x1; _fr.z = _y0; _fr.w = _y1;          \
      bf16x8 _pa = __builtin_bit_cast(bf16x8, _fr);                           \
      cacc[0] = __builtin_amdgcn_mfma_f32_32x32x16_bf16(_pa, vb[2*_s2+0], cacc[0], 0, 0, 0); \
      cacc[1] = __builtin_amdgcn_mfma_f32_32x32x16_bf16(_pa, vb[2*_s2+1], cacc[1], 0, 0, 0); \
    }                                                                         \
  } while (0)

  bf16x8 kA[4], kB[4], kC[4], vA[4], vB[4], vC[4];
  LDK(kA, 0); LDV(vA, 0);
  LDK(kB, 1); LDV(vB, 1);
  LDK(kC, 2); LDV(vC, 2);

#pragma unroll 1
  for (int j = 0; j < 21; ++j) {
    const int t0 = 3 * j;
    COMPUTE(kA, vA, t0);
    { const int tn = t0 + 3; if (tn < 64) { LDK(kA, tn); LDV(vA, tn); } }
    COMPUTE(kB, vB, t0 + 1);
    { const int tn = t0 + 4; if (tn < 64) { LDK(kB, tn); LDV(vB, tn); } }
    COMPUTE(kC, vC, t0 + 2);
    { const int tn = t0 + 5; if (tn < 64) { LDK(kC, tn); LDV(vC, tn); } }
    __builtin_amdgcn_s_barrier();   // drift clamp only: no waitcnt, loads stay in flight
  }
  COMPUTE(kA, vA, 63);

#undef LDK
#undef LDV
#undef COMPUTE

  rsum += __shfl_xor(rsum, 32, 64);
  const float inv = 1.0f / rsum;            // lane i (i<32) holds q0+i
  if (lane < 32) inv_g[(size_t)bh * S_LEN + q0 + lane] = inv;

  float sc[16];
#pragma unroll
  for (int r = 0; r < 16; ++r)
    sc[r] = __shfl(inv, (r & 3) + 8 * (r >> 2) + 4 * hi, 64);
#pragma unroll
  for (int db = 0; db < 2; ++db)
#pragma unroll
    for (int r = 0; r < 16; ++r) {
      const int qq = (r & 3) + 8 * (r >> 2) + 4 * hi;
      ctx_out[((size_t)(b * S_LEN + q0 + qq)) * DMODEL + h * DHEAD + db * 32 + q_l] =
          f2bf(cacc[db][r] * sc[r]);
    }
}

// ---------------- fused tail v5: gemm_out (0..255) + L1-shared store w/ drift clamp ------
// R14 store branch + raw s_barrier per k-tile (same rationale as attn_pv: the 4 waves
// share the same 512-k K stream for 4 different q-groups; barrier keeps them inside L1).
__global__ __launch_bounds__(256) void tail_fused(
    const u16* __restrict__ ctx, const u16* __restrict__ wot, const float* __restrict__ bo,
    float* __restrict__ out,
    const u16* __restrict__ qh, const u16* __restrict__ kh,
    const float* __restrict__ mask, const float* __restrict__ inv_g,
    float* __restrict__ attn_out)
{
  if (blockIdx.x < 256) {
    const int gid = blockIdx.x;
    gemm_core<1>(ctx, wot, bo, out, 1.f, (gid >> 3) * 128, (gid & 7) * 128);
    return;
  }
  const int id = blockIdx.x - 256;          // 0..1023; 256 = 0 mod 8: XCD phase preserved
  const int tid = threadIdx.x;
  const int lane = tid & 63, w = tid >> 6;
  const int q_l = lane & 31, hi = lane >> 5;
  const int h = ((id & 7) << 1) | ((id >> 3) & 1);
  const int b = (id >> 4) & 1;
  const int bh = b * 16 + h;
  const int kseg = (id >> 5) & 3;           // 0..3: block-shared k segment
  const int qb8 = id >> 7;                  // 0..7
  const int q0 = qb8 * 256 + w * 64;        // wave-private 64-q block

  const u16* Qp = qh + (size_t)bh * S_LEN * DHEAD;
  const u16* Kp = kh + (size_t)bh * S_LEN * DHEAD;

  bf16x8 qfA[4], qfB[4];
  {
    const u16* qrA = Qp + (size_t)(q0 + q_l) * DHEAD + hi * 8;
    const u16* qrB = Qp + (size_t)(q0 + 32 + q_l) * DHEAD + hi * 8;
#pragma unroll
    for (int c = 0; c < 4; ++c) {
      qfA[c] = *reinterpret_cast<const bf16x8*>(qrA + c * 16);
      qfB[c] = *reinterpret_cast<const bf16x8*>(qrB + c * 16);
    }
  }

  float myinvA[16], myinvB[16];
#pragma unroll
  for (int r = 0; r < 16; ++r) {
    const int rq = (r & 3) + 8 * (r >> 2) + 4 * hi;
    myinvA[r] = inv_g[(size_t)bh * S_LEN + q0 + rq];
    myinvB[r] = inv_g[(size_t)bh * S_LEN + q0 + 32 + rq];
  }

  const int k0w = kseg * 512;
  float mval[16];
#pragma unroll
  for (int t = 0; t < 16; ++t)
    mval[t] = mask[(size_t)b * S_LEN + k0w + t * 32 + q_l] * -1e9f;

  float* baseA = attn_out + ((size_t)bh * S_LEN + q0 + 4 * hi) * S_LEN + k0w + q_l;
  float* baseB = attn_out + ((size_t)bh * S_LEN + q0 + 32 + 4 * hi) * S_LEN + k0w + q_l;

  bf16x8 kc[4], kn[4];
  {
    const u16* kr0 = Kp + (size_t)(k0w + q_l) * DHEAD + hi * 8;
#pragma unroll
    for (int c = 0; c < 4; ++c) kc[c] = *reinterpret_cast<const bf16x8*>(kr0 + c * 16);
  }

#pragma unroll
  for (int t = 0; t < 16; ++t) {
    if (t < 15) {
      const u16* krow = Kp + (size_t)(k0w + (t + 1) * 32 + q_l) * DHEAD + hi * 8;
#pragma unroll
      for (int c = 0; c < 4; ++c) kn[c] = *reinterpret_cast<const bf16x8*>(krow + c * 16);
    }
    // sub-tile A
    {
      f32x16 a0, a1;
#pragma unroll
      for (int r = 0; r < 16; ++r) { a0[r] = 0.f; a1[r] = 0.f; }
      a0 = __builtin_amdgcn_mfma_f32_32x32x16_bf16(qfA[0], kc[0], a0, 0, 0, 0);
      a0 = __builtin_amdgcn_mfma_f32_32x32x16_bf16(qfA[1], kc[1], a0, 0, 0, 0);
      a1 = __builtin_amdgcn_mfma_f32_32x32x16_bf16(qfA[2], kc[2], a1, 0, 0, 0);
      a1 = __builtin_amdgcn_mfma_f32_32x32x16_bf16(qfA[3], kc[3], a1, 0, 0, 0);
#pragma unroll
      for (int r = 0; r < 16; ++r) {
        const float pv = __expf(a0[r] + a1[r] + mval[t]) * myinvA[r];
        const int rr = (r & 3) + 8 * (r >> 2);
        __builtin_nontemporal_store(pv, &baseA[(size_t)rr * S_LEN + t * 32]);
      }
    }
    // sub-tile B (reuses kc and the a0/a1 register pair)
    {
      f32x16 a0, a1;
#pragma unroll
      for (int r = 0; r < 16; ++r) { a0[r] = 0.f; a1[r] = 0.f; }
      a0 = __builtin_amdgcn_mfma_f32_32x32x16_bf16(qfB[0], kc[0], a0, 0, 0, 0);
      a0 = __builtin_amdgcn_mfma_f32_32x32x16_bf16(qfB[1], kc[1], a0, 0, 0, 0);
      a1 = __builtin_amdgcn_mfma_f32_32x32x16_bf16(qfB[2], kc[2], a1, 0, 0, 0);
      a1 = __builtin_amdgcn_mfma_f32_32x32x16_bf16(qfB[3], kc[3], a1, 0, 0, 0);
#pragma unroll
      for (int r = 0; r < 16; ++r) {
        const float pv = __expf(a0[r] + a1[r] + mval[t]) * myinvB[r];
        const int rr = (r & 3) + 8 * (r >> 2);
        __builtin_nontemporal_store(pv, &baseB[(size_t)rr * S_LEN + t * 32]);
      }
    }
#pragma unroll
    for (int c = 0; c < 4; ++c) kc[c] = kn[c];
    __builtin_amdgcn_s_barrier();   // drift clamp only
  }
}

extern "C" void kernel_launch(void* const* d_in, const int* in_sizes, int n_in,
                              void* d_out, int out_size, void* d_ws, size_t ws_size,
                              hipStream_t stream)
{
  (void)in_sizes; (void)n_in; (void)out_size; (void)ws_size;
  const float* v    = (const float*)d_in[0];
  const float* k    = (const float*)d_in[1];
  const float* q    = (const float*)d_in[2];
  const float* mask = (const float*)d_in[3];
  const float* Wq   = (const float*)d_in[4];
  const float* bq   = (const float*)d_in[5];
  const float* Wk   = (const float*)d_in[6];
  const float* bk   = (const float*)d_in[7];
  const float* Wv   = (const float*)d_in[8];
  const float* bv   = (const float*)d_in[9];
  const float* Wo   = (const float*)d_in[10];
  const float* bo   = (const float*)d_in[11];

  u16* ws16 = (u16*)d_ws;
  u16* xq  = ws16;
  u16* xk  = ws16 + (size_t)1 * NE;
  u16* xv  = ws16 + (size_t)2 * NE;
  u16* qh  = ws16 + (size_t)3 * NE;
  u16* kh  = ws16 + (size_t)4 * NE;
  u16* vh  = ws16 + (size_t)5 * NE;
  u16* wqt = ws16 + (size_t)6 * NE;
  u16* wkt = wqt + WN;
  u16* wvt = wkt + WN;
  u16* wot = wvt + WN;
  float* inv_g = (float*)(wot + WN);   // 32*2048 f32 = 256 KB
  u16* vt  = xq;   // alias: xq dead after gemm_qkv
  u16* ctx = xk;   // alias: xk dead after gemm_qkv

  float* outp  = (float*)d_out;
  float* attnp = outp + (size_t)NE;

  cvt_inputs<<<dim3(1024), dim3(256), 0, stream>>>(q, k, v, xq, xk, xv);
  wtrans<<<dim3(16, 16, 4), dim3(256), 0, stream>>>(Wq, Wk, Wv, Wo, wqt, wkt, wvt, wot);
  gemm_qkv<<<dim3(8, 32, 3), dim3(256), 0, stream>>>(xq, xk, xv, wqt, wkt, wvt,
                                                     bq, bk, bv, qh, kh, vh);
  vtrans<<<dim3(1024), dim3(256), 0, stream>>>(vh, vt);
  attn_pv<<<dim3(512), dim3(256), 0, stream>>>(qh, kh, vt, mask, inv_g, ctx);
  tail_fused<<<dim3(1280), dim3(256), 0, stream>>>(ctx, wot, bo, outp,
                                                   qh, kh, mask, inv_g, attnp);
}

// Round 16
// 298.552 us; speedup vs baseline: 1.0820x; 1.0820x over previous
//
#include <hip/hip_runtime.h>
#include <stdint.h>

#define S_LEN 2048
#define DMODEL 1024
#define NHEAD 16
#define DHEAD 64
#define NBATCH 2
#define NE 4194304   // NBATCH*S_LEN*DMODEL
#define WN 1048576   // DMODEL*DMODEL

typedef unsigned short u16;
typedef float f32x16 __attribute__((ext_vector_type(16)));
typedef __bf16 bf16x8 __attribute__((ext_vector_type(8)));

__device__ __forceinline__ u16 f2bf(float x) {
  union { float f; unsigned u; } v; v.f = x;
  unsigned r = v.u + 0x7fffu + ((v.u >> 16) & 1u);
  return (u16)(r >> 16);
}
__device__ __forceinline__ unsigned cvt_pk_bf16(float lo, float hi) {
  unsigned r;
  asm("v_cvt_pk_bf16_f32 %0, %1, %2" : "=v"(r) : "v"(lo), "v"(hi));
  return r;
}
__device__ __forceinline__ void gld_lds16(const void* g, void* l) {
  __builtin_amdgcn_global_load_lds(
      (const __attribute__((address_space(1))) unsigned*)g,
      (__attribute__((address_space(3))) unsigned*)l, 16, 0, 0);
}

// ---------------- convert q,k,v f32 -> bf16 ----------------
__global__ __launch_bounds__(256) void cvt_inputs(
    const float* __restrict__ q, const float* __restrict__ k, const float* __restrict__ v,
    u16* __restrict__ xq, u16* __restrict__ xk, u16* __restrict__ xv)
{
  int i = blockIdx.x * 256 + threadIdx.x;
  const int stride = gridDim.x * 256;
  for (; i < NE / 4; i += stride) {
    float4 a = ((const float4*)q)[i];
    float4 b = ((const float4*)k)[i];
    float4 c = ((const float4*)v)[i];
    ushort4 oa, ob, oc;
    oa.x = f2bf(a.x); oa.y = f2bf(a.y); oa.z = f2bf(a.z); oa.w = f2bf(a.w);
    ob.x = f2bf(b.x); ob.y = f2bf(b.y); ob.z = f2bf(b.z); ob.w = f2bf(b.w);
    oc.x = f2bf(c.x); oc.y = f2bf(c.y); oc.z = f2bf(c.z); oc.w = f2bf(c.w);
    ((ushort4*)xq)[i] = oa;
    ((ushort4*)xk)[i] = ob;
    ((ushort4*)xv)[i] = oc;
  }
}

// ---------------- convert + transpose weights: W[k][n] -> WT[n][k] bf16 ----------------
__global__ __launch_bounds__(256) void wtrans(
    const float* __restrict__ Wq, const float* __restrict__ Wk,
    const float* __restrict__ Wv, const float* __restrict__ Wo,
    u16* __restrict__ oq, u16* __restrict__ ok, u16* __restrict__ ov, u16* __restrict__ oo)
{
  __shared__ u16 t[64][65];
  const float* W; u16* O;
  if (blockIdx.z == 0)      { W = Wq; O = oq; }
  else if (blockIdx.z == 1) { W = Wk; O = ok; }
  else if (blockIdx.z == 2) { W = Wv; O = ov; }
  else                      { W = Wo; O = oo; }
  const int tid = threadIdx.x;
  const int r0 = blockIdx.y * 64, c0 = blockIdx.x * 64;
#pragma unroll
  for (int i = 0; i < 4; ++i) {
    const int row = i * 16 + (tid >> 4);
    const int col = (tid & 15) * 4;
    float4 wv = *(const float4*)(W + (size_t)(r0 + row) * DMODEL + c0 + col);
    t[row][col + 0] = f2bf(wv.x);
    t[row][col + 1] = f2bf(wv.y);
    t[row][col + 2] = f2bf(wv.z);
    t[row][col + 3] = f2bf(wv.w);
  }
  __syncthreads();
#pragma unroll
  for (int i = 0; i < 4; ++i) {
    const int row = i * 16 + (tid >> 4);
    const int col = (tid & 15) * 4;
    ushort4 o;
    o.x = t[col + 0][row]; o.y = t[col + 1][row];
    o.z = t[col + 2][row]; o.w = t[col + 3][row];
    *(ushort4*)(O + (size_t)(c0 + row) * DMODEL + r0 + col) = o;
  }
}

// ---------------- 128x128 bf16 MFMA GEMM, B^T input, global_load_lds staging ----------------
template <int OUTMODE>
__device__ __forceinline__ void gemm_core(
    const u16* __restrict__ A, const u16* __restrict__ Bt,
    const float* __restrict__ bias, void* __restrict__ outp,
    float scale, int m0, int n0)
{
  __shared__ u16 As[128 * 32];
  __shared__ u16 Bs[128 * 32];
  const int tid = threadIdx.x;
  const int lane = tid & 63, w = tid >> 6;
  const int q_l = lane & 31, hi = lane >> 5;
  const int wr = w >> 1, wc = w & 1;

  f32x16 acc[2][2];
#pragma unroll
  for (int a = 0; a < 2; ++a)
#pragma unroll
    for (int b = 0; b < 2; ++b)
#pragma unroll
      for (int r = 0; r < 16; ++r) acc[a][b][r] = 0.f;

  const u16* srcA = A + (size_t)(m0 + (tid >> 2)) * DMODEL + (tid & 3) * 8;
  const u16* srcB = Bt + (size_t)(n0 + (tid >> 2)) * DMODEL + (tid & 3) * 8;
  u16* dstA = As + w * 512;
  u16* dstB = Bs + w * 512;

  for (int kt = 0; kt < DMODEL; kt += 32) {
    gld_lds16(srcA + kt, dstA);
    gld_lds16(srcA + kt + (size_t)64 * DMODEL, dstA + 2048);
    gld_lds16(srcB + kt, dstB);
    gld_lds16(srcB + kt + (size_t)64 * DMODEL, dstB + 2048);
    __syncthreads();
#pragma unroll
    for (int kk = 0; kk < 2; ++kk) {
      bf16x8 af[2], bfv[2];
#pragma unroll
      for (int mb = 0; mb < 2; ++mb)
        af[mb] = *reinterpret_cast<const bf16x8*>(&As[(wr * 64 + mb * 32 + q_l) * 32 + kk * 16 + hi * 8]);
#pragma unroll
      for (int nb = 0; nb < 2; ++nb)
        bfv[nb] = *reinterpret_cast<const bf16x8*>(&Bs[(wc * 64 + nb * 32 + q_l) * 32 + kk * 16 + hi * 8]);
#pragma unroll
      for (int mb = 0; mb < 2; ++mb)
#pragma unroll
        for (int nb = 0; nb < 2; ++nb)
          acc[mb][nb] = __builtin_amdgcn_mfma_f32_32x32x16_bf16(af[mb], bfv[nb], acc[mb][nb], 0, 0, 0);
    }
    __syncthreads();
  }

#pragma unroll
  for (int mb = 0; mb < 2; ++mb) {
#pragma unroll
    for (int nb = 0; nb < 2; ++nb) {
      const int n = n0 + wc * 64 + nb * 32 + q_l;
      const float bn = bias[n];
#pragma unroll
      for (int r = 0; r < 16; ++r) {
        const int m = m0 + wr * 64 + mb * 32 + (r & 3) + 8 * (r >> 2) + 4 * hi;
        const float val = (acc[mb][nb][r] + bn) * scale;
        if (OUTMODE == 0) {
          const int bb = m >> 11, s = m & 2047, hh = n >> 6, d = n & 63;
          ((u16*)outp)[(((size_t)(bb * NHEAD + hh)) * S_LEN + s) * DHEAD + d] = f2bf(val);
        } else {
          ((float*)outp)[(size_t)m * DMODEL + n] = val;
        }
      }
    }
  }
}

__global__ __launch_bounds__(256) void gemm_qkv(
    const u16* __restrict__ xq, const u16* __restrict__ xk, const u16* __restrict__ xv,
    const u16* __restrict__ wqt, const u16* __restrict__ wkt, const u16* __restrict__ wvt,
    const float* __restrict__ bq, const float* __restrict__ bk, const float* __restrict__ bv,
    u16* __restrict__ qh, u16* __restrict__ kh, u16* __restrict__ vh)
{
  const u16 *A, *Bt; const float* bias; u16* O; float scale;
  if (blockIdx.z == 0)      { A = xq; Bt = wqt; bias = bq; O = qh; scale = 0.125f; }
  else if (blockIdx.z == 1) { A = xk; Bt = wkt; bias = bk; O = kh; scale = 1.f; }
  else                      { A = xv; Bt = wvt; bias = bv; O = vh; scale = 1.f; }
  gemm_core<0>(A, Bt, bias, O, scale, blockIdx.y * 128, blockIdx.x * 128);
}

// ---------------- transpose Vh[bh][s][d] -> Vt[bh][d][s], producer-XCD aligned ----------------
__global__ __launch_bounds__(256) void vtrans(const u16* __restrict__ vh, u16* __restrict__ vt)
{
  __shared__ u16 t[64][72];
  const int tid = threadIdx.x;
  const int id = blockIdx.x;
  const int h = ((id & 7) << 1) | ((id >> 3) & 1);
  const int b = (id >> 4) & 1;
  const int bh = b * 16 + h;
  const int s0 = (id >> 5) * 64;
  const u16* src = vh + (size_t)bh * S_LEN * DHEAD;
  u16* dst = vt + (size_t)bh * DHEAD * S_LEN;
#pragma unroll
  for (int i = 0; i < 2; ++i) {
    const int row = i * 32 + (tid >> 3);
    const int c8 = (tid & 7) * 8;
    *(uint4*)&t[row][c8] = *(const uint4*)(src + (size_t)(s0 + row) * DHEAD + c8);
  }
  __syncthreads();
#pragma unroll
  for (int i = 0; i < 2; ++i) {
    const int d = i * 32 + (tid >> 3);
    const int c8 = (tid & 7) * 8;
    unsigned p0 = (unsigned)t[c8 + 0][d] | ((unsigned)t[c8 + 1][d] << 16);
    unsigned p1 = (unsigned)t[c8 + 2][d] | ((unsigned)t[c8 + 3][d] << 16);
    unsigned p2 = (unsigned)t[c8 + 4][d] | ((unsigned)t[c8 + 5][d] << 16);
    unsigned p3 = (unsigned)t[c8 + 6][d] | ((unsigned)t[c8 + 7][d] << 16);
    uint4 o; o.x = p0; o.y = p1; o.z = p2; o.w = p3;
    *(uint4*)(dst + (size_t)d * S_LEN + s0 + c8) = o;
  }
}

// ---------------- attn kernel A v10: q-merge x2 (64 q-rows/wave), depth-1 prefetch ------
// grid 1024 x 64 threads, producer-XCD-aligned decode. Each wave sweeps all 64 k-tiles
// ONCE for TWO 32-q tiles: K/V registers shared by both -> K/V cache reads halve
// (1GB -> 512MB). Tile-A processed fully before tile-B (one QK temp pair live -> no
// spill); depth-1 K/V prefetch (R7-proven; depth-2 was null, saves 32 VGPR).
__global__ __launch_bounds__(64, 2) void attn_pv(
    const u16* __restrict__ qh, const u16* __restrict__ kh,
    const u16* __restrict__ vt, const float* __restrict__ mask,
    float* __restrict__ inv_g, u16* __restrict__ ctx_out)
{
  const int lane = threadIdx.x;
  const int q_l = lane & 31, hi = lane >> 5;
  const int id = blockIdx.x;               // 0..1023
  const int h = ((id & 7) << 1) | ((id >> 3) & 1);
  const int b = (id >> 4) & 1;
  const int bh = b * 16 + h;
  const int qb = id >> 5;                  // 0..31
  const int q0 = qb * 64;                  // two 32-q tiles: [q0,q0+32) and [q0+32,q0+64)

  const u16* Qp = qh + (size_t)bh * S_LEN * DHEAD;
  const u16* Kp = kh + (size_t)bh * S_LEN * DHEAD;
  const u16* Vp = vt + (size_t)bh * DHEAD * S_LEN;
  const float* mrow = mask + (size_t)b * S_LEN;

  bf16x8 qfA[4], qfB[4];
  {
    const u16* qrA = Qp + (size_t)(q0 + q_l) * DHEAD + hi * 8;
    const u16* qrB = Qp + (size_t)(q0 + 32 + q_l) * DHEAD + hi * 8;
#pragma unroll
    for (int c = 0; c < 4; ++c) {
      qfA[c] = *reinterpret_cast<const bf16x8*>(qrA + c * 16);
      qfB[c] = *reinterpret_cast<const bf16x8*>(qrB + c * 16);
    }
  }

  float rsumA = 0.f, rsumB = 0.f;
  f32x16 caccA[2], caccB[2];
#pragma unroll
  for (int db = 0; db < 2; ++db)
#pragma unroll
    for (int r = 0; r < 16; ++r) { caccA[db][r] = 0.f; caccB[db][r] = 0.f; }

  bf16x8 kc[4], kn[4], vc[2][2], vn[2][2];
  {
    const u16* kr0 = Kp + (size_t)q_l * DHEAD + hi * 8;
#pragma unroll
    for (int c = 0; c < 4; ++c) kc[c] = *reinterpret_cast<const bf16x8*>(kr0 + c * 16);
#pragma unroll
    for (int s2 = 0; s2 < 2; ++s2)
#pragma unroll
      for (int db = 0; db < 2; ++db)
        vc[s2][db] = *reinterpret_cast<const bf16x8*>(
            Vp + (size_t)(db * 32 + q_l) * S_LEN + s2 * 16 + hi * 8);
  }

#pragma unroll 1
  for (int t = 0; t < 64; ++t) {
    const int k0 = t * 32;
    // prefetch next tile's K and V (independent of all compute below)
    if (t < 63) {
      const u16* krow = Kp + (size_t)(k0 + 32 + q_l) * DHEAD + hi * 8;
#pragma unroll
      for (int c = 0; c < 4; ++c) kn[c] = *reinterpret_cast<const bf16x8*>(krow + c * 16);
#pragma unroll
      for (int s2 = 0; s2 < 2; ++s2)
#pragma unroll
        for (int db = 0; db < 2; ++db)
          vn[s2][db] = *reinterpret_cast<const bf16x8*>(
              Vp + (size_t)(db * 32 + q_l) * S_LEN + k0 + 32 + s2 * 16 + hi * 8);
    }
    // ---- tile A ----
    {
      f32x16 a0, a1;
#pragma unroll
      for (int r = 0; r < 16; ++r) { a0[r] = 0.f; a1[r] = 0.f; }
      a0 = __builtin_amdgcn_mfma_f32_32x32x16_bf16(kc[0], qfA[0], a0, 0, 0, 0);
      a0 = __builtin_amdgcn_mfma_f32_32x32x16_bf16(kc[1], qfA[1], a0, 0, 0, 0);
      a1 = __builtin_amdgcn_mfma_f32_32x32x16_bf16(kc[2], qfA[2], a1, 0, 0, 0);
      a1 = __builtin_amdgcn_mfma_f32_32x32x16_bf16(kc[3], qfA[3], a1, 0, 0, 0);
      float p[16];
#pragma unroll
      for (int g = 0; g < 4; ++g) {
        const float4 mk = *(const float4*)&mrow[k0 + 8 * g + 4 * hi];
        p[4 * g + 0] = __expf(a0[4 * g + 0] + a1[4 * g + 0] + mk.x * -1e9f);
        p[4 * g + 1] = __expf(a0[4 * g + 1] + a1[4 * g + 1] + mk.y * -1e9f);
        p[4 * g + 2] = __expf(a0[4 * g + 2] + a1[4 * g + 2] + mk.z * -1e9f);
        p[4 * g + 3] = __expf(a0[4 * g + 3] + a1[4 * g + 3] + mk.w * -1e9f);
        rsumA += (p[4 * g + 0] + p[4 * g + 1]) + (p[4 * g + 2] + p[4 * g + 3]);
      }
      unsigned pk[8];
#pragma unroll
      for (int g = 0; g < 4; ++g) {
        pk[2 * g + 0] = cvt_pk_bf16(p[4 * g + 0], p[4 * g + 1]);
        pk[2 * g + 1] = cvt_pk_bf16(p[4 * g + 2], p[4 * g + 3]);
      }
#pragma unroll
      for (int s2 = 0; s2 < 2; ++s2) {
        unsigned x0 = pk[4 * s2 + 0], y0 = pk[4 * s2 + 2];
        unsigned x1 = pk[4 * s2 + 1], y1 = pk[4 * s2 + 3];
        asm volatile("v_permlane32_swap_b32 %0, %1" : "+v"(x0), "+v"(y0));
        asm volatile("v_permlane32_swap_b32 %0, %1" : "+v"(x1), "+v"(y1));
        uint4 fr; fr.x = x0; fr.y = x1; fr.z = y0; fr.w = y1;
        bf16x8 pa = __builtin_bit_cast(bf16x8, fr);
#pragma unroll
        for (int db = 0; db < 2; ++db)
          caccA[db] = __builtin_amdgcn_mfma_f32_32x32x16_bf16(pa, vc[s2][db], caccA[db], 0, 0, 0);
      }
    }
    // ---- tile B (reuses kc/vc) ----
    {
      f32x16 a0, a1;
#pragma unroll
      for (int r = 0; r < 16; ++r) { a0[r] = 0.f; a1[r] = 0.f; }
      a0 = __builtin_amdgcn_mfma_f32_32x32x16_bf16(kc[0], qfB[0], a0, 0, 0, 0);
      a0 = __builtin_amdgcn_mfma_f32_32x32x16_bf16(kc[1], qfB[1], a0, 0, 0, 0);
      a1 = __builtin_amdgcn_mfma_f32_32x32x16_bf16(kc[2], qfB[2], a1, 0, 0, 0);
      a1 = __builtin_amdgcn_mfma_f32_32x32x16_bf16(kc[3], qfB[3], a1, 0, 0, 0);
      float p[16];
#pragma unroll
      for (int g = 0; g < 4; ++g) {
        const float4 mk = *(const float4*)&mrow[k0 + 8 * g + 4 * hi];
        p[4 * g + 0] = __expf(a0[4 * g + 0] + a1[4 * g + 0] + mk.x * -1e9f);
        p[4 * g + 1] = __expf(a0[4 * g + 1] + a1[4 * g + 1] + mk.y * -1e9f);
        p[4 * g + 2] = __expf(a0[4 * g + 2] + a1[4 * g + 2] + mk.z * -1e9f);
        p[4 * g + 3] = __expf(a0[4 * g + 3] + a1[4 * g + 3] + mk.w * -1e9f);
        rsumB += (p[4 * g + 0] + p[4 * g + 1]) + (p[4 * g + 2] + p[4 * g + 3]);
      }
      unsigned pk[8];
#pragma unroll
      for (int g = 0; g < 4; ++g) {
        pk[2 * g + 0] = cvt_pk_bf16(p[4 * g + 0], p[4 * g + 1]);
        pk[2 * g + 1] = cvt_pk_bf16(p[4 * g + 2], p[4 * g + 3]);
      }
#pragma unroll
      for (int s2 = 0; s2 < 2; ++s2) {
        unsigned x0 = pk[4 * s2 + 0], y0 = pk[4 * s2 + 2];
        unsigned x1 = pk[4 * s2 + 1], y1 = pk[4 * s2 + 3];
        asm volatile("v_permlane32_swap_b32 %0, %1" : "+v"(x0), "+v"(y0));
        asm volatile("v_permlane32_swap_b32 %0, %1" : "+v"(x1), "+v"(y1));
        uint4 fr; fr.x = x0; fr.y = x1; fr.z = y0; fr.w = y1;
        bf16x8 pb = __builtin_bit_cast(bf16x8, fr);
#pragma unroll
        for (int db = 0; db < 2; ++db)
          caccB[db] = __builtin_amdgcn_mfma_f32_32x32x16_bf16(pb, vc[s2][db], caccB[db], 0, 0, 0);
      }
    }
#pragma unroll
    for (int c = 0; c < 4; ++c) kc[c] = kn[c];
#pragma unroll
    for (int s2 = 0; s2 < 2; ++s2)
#pragma unroll
      for (int db = 0; db < 2; ++db) vc[s2][db] = vn[s2][db];
  }

  rsumA += __shfl_xor(rsumA, 32, 64);
  rsumB += __shfl_xor(rsumB, 32, 64);
  const float invA = 1.0f / rsumA;          // lane i (i<32): q-row q0+i
  const float invB = 1.0f / rsumB;          // lane i (i<32): q-row q0+32+i
  if (lane < 32) {
    inv_g[(size_t)bh * S_LEN + q0 + lane] = invA;
    inv_g[(size_t)bh * S_LEN + q0 + 32 + lane] = invB;
  }

  float scA[16], scB[16];
#pragma unroll
  for (int r = 0; r < 16; ++r) {
    const int src = (r & 3) + 8 * (r >> 2) + 4 * hi;
    scA[r] = __shfl(invA, src, 64);
    scB[r] = __shfl(invB, src, 64);
  }
#pragma unroll
  for (int db = 0; db < 2; ++db)
#pragma unroll
    for (int r = 0; r < 16; ++r) {
      const int qq = (r & 3) + 8 * (r >> 2) + 4 * hi;
      ctx_out[((size_t)(b * S_LEN + q0 + qq)) * DMODEL + h * DHEAD + db * 32 + q_l] =
          f2bf(caccA[db][r] * scA[r]);
      ctx_out[((size_t)(b * S_LEN + q0 + 32 + qq)) * DMODEL + h * DHEAD + db * 32 + q_l] =
          f2bf(caccB[db][r] * scB[r]);
    }
}

// ---------------- fused tail v3 (R13 verbatim): gemm_out (0..255) + q-merged attn_store --
__global__ __launch_bounds__(256) void tail_fused(
    const u16* __restrict__ ctx, const u16* __restrict__ wot, const float* __restrict__ bo,
    float* __restrict__ out,
    const u16* __restrict__ qh, const u16* __restrict__ kh,
    const float* __restrict__ mask, const float* __restrict__ inv_g,
    float* __restrict__ attn_out)
{
  if (blockIdx.x < 256) {
    const int gid = blockIdx.x;
    gemm_core<1>(ctx, wot, bo, out, 1.f, (gid >> 3) * 128, (gid & 7) * 128);
    return;
  }
  const int id = blockIdx.x - 256;          // 0..1023; 256 = 0 mod 8: XCD phase preserved
  const int tid = threadIdx.x;
  const int lane = tid & 63, w = tid >> 6;
  const int q_l = lane & 31, hi = lane >> 5;
  const int h = ((id & 7) << 1) | ((id >> 3) & 1);
  const int b = (id >> 4) & 1;
  const int bh = b * 16 + h;
  const int qb = id >> 5;                   // 0..31
  const int q0 = qb * 64;                   // 64-q block (two 32-q tiles)

  const u16* Qp = qh + (size_t)bh * S_LEN * DHEAD;
  const u16* Kp = kh + (size_t)bh * S_LEN * DHEAD;

  bf16x8 qfA[4], qfB[4];
  {
    const u16* qrA = Qp + (size_t)(q0 + q_l) * DHEAD + hi * 8;
    const u16* qrB = Qp + (size_t)(q0 + 32 + q_l) * DHEAD + hi * 8;
#pragma unroll
    for (int c = 0; c < 4; ++c) {
      qfA[c] = *reinterpret_cast<const bf16x8*>(qrA + c * 16);
      qfB[c] = *reinterpret_cast<const bf16x8*>(qrB + c * 16);
    }
  }

  float myinvA[16], myinvB[16];
#pragma unroll
  for (int r = 0; r < 16; ++r) {
    const int rq = (r & 3) + 8 * (r >> 2) + 4 * hi;
    myinvA[r] = inv_g[(size_t)bh * S_LEN + q0 + rq];
    myinvB[r] = inv_g[(size_t)bh * S_LEN + q0 + 32 + rq];
  }

  const int k0w = w * 512;
  float mval[16];
#pragma unroll
  for (int t = 0; t < 16; ++t)
    mval[t] = mask[(size_t)b * S_LEN + k0w + t * 32 + q_l] * -1e9f;

  float* baseA = attn_out + ((size_t)bh * S_LEN + q0 + 4 * hi) * S_LEN + k0w + q_l;
  float* baseB = attn_out + ((size_t)bh * S_LEN + q0 + 32 + 4 * hi) * S_LEN + k0w + q_l;

  bf16x8 kc[4], kn[4];
  {
    const u16* kr0 = Kp + (size_t)(k0w + q_l) * DHEAD + hi * 8;
#pragma unroll
    for (int c = 0; c < 4; ++c) kc[c] = *reinterpret_cast<const bf16x8*>(kr0 + c * 16);
  }

#pragma unroll
  for (int t = 0; t < 16; ++t) {
    if (t < 15) {
      const u16* krow = Kp + (size_t)(k0w + (t + 1) * 32 + q_l) * DHEAD + hi * 8;
#pragma unroll
      for (int c = 0; c < 4; ++c) kn[c] = *reinterpret_cast<const bf16x8*>(krow + c * 16);
    }
    // sub-tile A
    {
      f32x16 a0, a1;
#pragma unroll
      for (int r = 0; r < 16; ++r) { a0[r] = 0.f; a1[r] = 0.f; }
      a0 = __builtin_amdgcn_mfma_f32_32x32x16_bf16(qfA[0], kc[0], a0, 0, 0, 0);
      a0 = __builtin_amdgcn_mfma_f32_32x32x16_bf16(qfA[1], kc[1], a0, 0, 0, 0);
      a1 = __builtin_amdgcn_mfma_f32_32x32x16_bf16(qfA[2], kc[2], a1, 0, 0, 0);
      a1 = __builtin_amdgcn_mfma_f32_32x32x16_bf16(qfA[3], kc[3], a1, 0, 0, 0);
#pragma unroll
      for (int r = 0; r < 16; ++r) {
        const float pv = __expf(a0[r] + a1[r] + mval[t]) * myinvA[r];
        const int rr = (r & 3) + 8 * (r >> 2);
        __builtin_nontemporal_store(pv, &baseA[(size_t)rr * S_LEN + t * 32]);
      }
    }
    // sub-tile B (reuses kc and the a0/a1 register pair)
    {
      f32x16 a0, a1;
#pragma unroll
      for (int r = 0; r < 16; ++r) { a0[r] = 0.f; a1[r] = 0.f; }
      a0 = __builtin_amdgcn_mfma_f32_32x32x16_bf16(qfB[0], kc[0], a0, 0, 0, 0);
      a0 = __builtin_amdgcn_mfma_f32_32x32x16_bf16(qfB[1], kc[1], a0, 0, 0, 0);
      a1 = __builtin_amdgcn_mfma_f32_32x32x16_bf16(qfB[2], kc[2], a1, 0, 0, 0);
      a1 = __builtin_amdgcn_mfma_f32_32x32x16_bf16(qfB[3], kc[3], a1, 0, 0, 0);
#pragma unroll
      for (int r = 0; r < 16; ++r) {
        const float pv = __expf(a0[r] + a1[r] + mval[t]) * myinvB[r];
        const int rr = (r & 3) + 8 * (r >> 2);
        __builtin_nontemporal_store(pv, &baseB[(size_t)rr * S_LEN + t * 32]);
      }
    }
#pragma unroll
    for (int c = 0; c < 4; ++c) kc[c] = kn[c];
  }
}

extern "C" void kernel_launch(void* const* d_in, const int* in_sizes, int n_in,
                              void* d_out, int out_size, void* d_ws, size_t ws_size,
                              hipStream_t stream)
{
  (void)in_sizes; (void)n_in; (void)out_size; (void)ws_size;
  const float* v    = (const float*)d_in[0];
  const float* k    = (const float*)d_in[1];
  const float* q    = (const float*)d_in[2];
  const float* mask = (const float*)d_in[3];
  const float* Wq   = (const float*)d_in[4];
  const float* bq   = (const float*)d_in[5];
  const float* Wk   = (const float*)d_in[6];
  const float* bk   = (const float*)d_in[7];
  const float* Wv   = (const float*)d_in[8];
  const float* bv   = (const float*)d_in[9];
  const float* Wo   = (const float*)d_in[10];
  const float* bo   = (const float*)d_in[11];

  u16* ws16 = (u16*)d_ws;
  u16* xq  = ws16;
  u16* xk  = ws16 + (size_t)1 * NE;
  u16* xv  = ws16 + (size_t)2 * NE;
  u16* qh  = ws16 + (size_t)3 * NE;
  u16* kh  = ws16 + (size_t)4 * NE;
  u16* vh  = ws16 + (size_t)5 * NE;
  u16* wqt = ws16 + (size_t)6 * NE;
  u16* wkt = wqt + WN;
  u16* wvt = wkt + WN;
  u16* wot = wvt + WN;
  float* inv_g = (float*)(wot + WN);   // 32*2048 f32 = 256 KB
  u16* vt  = xq;   // alias: xq dead after gemm_qkv
  u16* ctx = xk;   // alias: xk dead after gemm_qkv

  float* outp  = (float*)d_out;
  float* attnp = outp + (size_t)NE;

  cvt_inputs<<<dim3(1024), dim3(256), 0, stream>>>(q, k, v, xq, xk, xv);
  wtrans<<<dim3(16, 16, 4), dim3(256), 0, stream>>>(Wq, Wk, Wv, Wo, wqt, wkt, wvt, wot);
  gemm_qkv<<<dim3(8, 32, 3), dim3(256), 0, stream>>>(xq, xk, xv, wqt, wkt, wvt,
                                                     bq, bk, bv, qh, kh, vh);
  vtrans<<<dim3(1024), dim3(256), 0, stream>>>(vh, vt);
  attn_pv<<<dim3(1024), dim3(64), 0, stream>>>(qh, kh, vt, mask, inv_g, ctx);
  tail_fused<<<dim3(1280), dim3(256), 0, stream>>>(ctx, wot, bo, outp,
                                                   qh, kh, mask, inv_g, attnp);
}